// Round 17
// baseline (336.083 us; speedup 1.0000x reference)
//
#include <hip/hip_runtime.h>
#include <math.h>

typedef __attribute__((ext_vector_type(8))) _Float16 half8;
typedef __attribute__((ext_vector_type(4))) _Float16 half4;
typedef __attribute__((ext_vector_type(4))) float f32x4;

#define B_TOT 65536
#define LOG2PI_F 1.8378770664093453f
#define HALF_N_LOG2PI (0.5f * 64.0f * LOG2PI_F)
#define LOG_1EM8 (-18.420680743952367f)

// ws layout (bytes)
#define WS_W2S  0                      // 2 MiB   fp16 packed+swizzled [32kt][1024n][32kk']
#define WS_W1P  (2u*1024*1024)         // 128 KiB fp16 packed [2kt][1024n][32kk] (plain)
#define WS_LPS  (4u*1024*1024)         // 2 MiB   float lps[65536][8]
#define WS_PART (6u*1024*1024)         // 1 KiB   float partials[256]
#define WS_HP   (8u*1024*1024)         // 128 MiB fp16 h packed [32kt][65536row][32kk']

typedef __attribute__((address_space(3))) unsigned int lds_u32;
typedef const __attribute__((address_space(1))) unsigned int glb_u32;

__device__ __forceinline__ void gload16(const void* g, void* l) {
    __builtin_amdgcn_global_load_lds((glb_u32*)g, (lds_u32*)l, 16, 0, 0);
}

__device__ __forceinline__ float eluf(float v) {
    return v > 0.0f ? v : expm1f(v);
}

// ---------------- pack W1: fp32 [64][1024] -> fp16 [kt][n][32kk] plain ----------------
__global__ __launch_bounds__(256)
void pack_w1(const float* __restrict__ src, _Float16* __restrict__ dst)
{
    __shared__ float ts[64][65];
    const int t = threadIdx.x;
    const int n0 = blockIdx.y * 64;
    {
        int r = t >> 2, c4 = t & 3;
        for (int i = 0; i < 4; ++i) {
            int cc = i * 4 + c4;
            float4 v = *(const float4*)&src[(size_t)r * 1024 + n0 + cc * 4];
            ts[r][cc*4+0] = v.x; ts[r][cc*4+1] = v.y;
            ts[r][cc*4+2] = v.z; ts[r][cc*4+3] = v.w;
        }
    }
    __syncthreads();
    {
        int n = t >> 2;
        for (int i = 0; i < 4; ++i) {
            int k = (i * 4 + (t & 3)) * 4;      // 0..60
            half4 h;
            h.x = (_Float16)ts[k+0][n];
            h.y = (_Float16)ts[k+1][n];
            h.z = (_Float16)ts[k+2][n];
            h.w = (_Float16)ts[k+3][n];
            size_t off = (size_t)(k >> 5) * 32768 + (size_t)(n0 + n) * 32 + (k & 31);
            *(half4*)&dst[off] = h;
        }
    }
}

// ---------------- pack W2: fp32 [1024][1024] -> fp16 [kt][n][32] with k-group swizzle ----------------
// element (k, n) stored at [k>>5][n][ (slot<<3) | (k&7) ], slot = ((k>>3)&3) ^ ((n>>1)&3)
__global__ __launch_bounds__(256)
void pack_w2s(const float* __restrict__ src, _Float16* __restrict__ dst)
{
    __shared__ float ts[64][65];
    const int t = threadIdx.x;
    const int k0 = blockIdx.x * 64, n0 = blockIdx.y * 64;
    {
        int r = t >> 2, c4 = t & 3;
        for (int i = 0; i < 4; ++i) {
            int cc = i * 4 + c4;
            float4 v = *(const float4*)&src[(size_t)(k0 + r) * 1024 + n0 + cc * 4];
            ts[r][cc*4+0] = v.x; ts[r][cc*4+1] = v.y;
            ts[r][cc*4+2] = v.z; ts[r][cc*4+3] = v.w;
        }
    }
    __syncthreads();
    {
        int n = t >> 2;
        int ng = n0 + n;
        for (int i = 0; i < 4; ++i) {
            int kl = (i * 4 + (t & 3)) * 4;      // local k, 4-aligned
            int k = k0 + kl;
            half4 h;
            h.x = (_Float16)ts[kl+0][n];
            h.y = (_Float16)ts[kl+1][n];
            h.z = (_Float16)ts[kl+2][n];
            h.w = (_Float16)ts[kl+3][n];
            int kk = k & 31;
            int slot = ((kk >> 3) ^ ((ng >> 1) & 3));
            size_t off = (size_t)(k >> 5) * 32768 + (size_t)ng * 32 + (slot << 3) + (kk & 7);
            *(half4*)&dst[off] = h;
        }
    }
}

// ---------------- K1: h = elu(x @ W1 + b1) -> packed fp16 hp, SWAPPED-operand MFMA ----------------
__global__ __launch_bounds__(512)
void k1_h(const float* __restrict__ x, const _Float16* __restrict__ W1P,
          const float* __restrict__ b1, _Float16* __restrict__ hp)
{
    __shared__ __align__(16) _Float16 xs[32 * 64];   // 4 KB
    const int t = threadIdx.x, q = blockIdx.x;
    const int w = t >> 6, l = t & 63, g = l >> 4, l15 = l & 15;

    {
        const float4* x4 = (const float4*)x;
        int r = t >> 4, c = t & 15;
        float4 v = x4[(size_t)(q * 32 + r) * 16 + c];
        float vv[4] = {v.x, v.y, v.z, v.w};
        #pragma unroll
        for (int i = 0; i < 4; ++i) {
            int col = c * 4 + i;
            xs[r * 64 + (col ^ ((r & 7) << 3))] = (_Float16)vv[i];
        }
    }
    __syncthreads();

    // wave w owns n in [w*128, w*128+128): 8 n-frags; 2 row-frags (32 rows)
    f32x4 acc[8][2];
    const float4* b1_4 = (const float4*)b1;
    #pragma unroll
    for (int nf = 0; nf < 8; ++nf) {
        float4 bv = b1_4[(w * 128 + nf * 16 + 4 * g) >> 2];   // bias by n (varies with rg!)
        acc[nf][0] = (f32x4){bv.x, bv.y, bv.z, bv.w};
        acc[nf][1] = acc[nf][0];
    }
    #pragma unroll
    for (int k0 = 0; k0 < 64; k0 += 32) {
        half8 bx[2];
        #pragma unroll
        for (int rf = 0; rf < 2; ++rf) {
            int row = rf * 16 + l15;
            bx[rf] = *(const half8*)&xs[row * 64 + ((k0 + 8 * g) ^ ((row & 7) << 3))];
        }
        #pragma unroll
        for (int nf = 0; nf < 8; ++nf) {
            size_t off = (size_t)(k0 >> 5) * 32768 + (size_t)(w * 128 + nf * 16 + l15) * 32 + 8 * g;
            half8 aw = *(const half8*)&W1P[off];
            #pragma unroll
            for (int rf = 0; rf < 2; ++rf)
                acc[nf][rf] = __builtin_amdgcn_mfma_f32_16x16x32_f16(aw, bx[rf], acc[nf][rf], 0, 0, 0);
        }
    }
    // epilogue: ELU -> half4 direct global stores (slot-swizzled hp layout, k2-compatible)
    #pragma unroll
    for (int nf = 0; nf < 8; ++nf) {
        int kt = w * 4 + (nf >> 1);
        int kkhi = (nf & 1) * 2 + (g >> 1);   // kk>>3
        int kklo = 4 * (g & 1);               // kk&7 base (rg adds 0..3)
        #pragma unroll
        for (int rf = 0; rf < 2; ++rf) {
            int grow = q * 32 + rf * 16 + l15;
            int slot = kkhi ^ ((grow >> 1) & 3);
            half4 h4;
            h4.x = (_Float16)eluf(acc[nf][rf][0]);
            h4.y = (_Float16)eluf(acc[nf][rf][1]);
            h4.z = (_Float16)eluf(acc[nf][rf][2]);
            h4.w = (_Float16)eluf(acc[nf][rf][3]);
            *(half4*)&hp[(size_t)kt * 2097152 + (size_t)grow * 32 + slot * 8 + kklo] = h4;
        }
    }
}

// ---------------- K2: fhatx = h @ W2 + b2, 3-buffer counted-vmcnt pipeline (T3/T4) ----------------
__global__ __launch_bounds__(512)
void k2_gemm2(const _Float16* __restrict__ hp, const _Float16* __restrict__ W2S,
              const float* __restrict__ b2, const float* __restrict__ y,
              float* __restrict__ lps)
{
    __shared__ __align__(16) _Float16 Ab[3][4096];   // 3 x 8 KB  [row' 128][32k]
    __shared__ __align__(16) _Float16 Bb[3][8192];   // 3 x 16 KB [n' 256][32k]
    __shared__ float lpp[128][2][2];                 // 2 KB

    const int t = threadIdx.x;
    const int bid = blockIdx.x;                 // 0..2047
    const int logical = (bid & 7) * 256 + (bid >> 3);   // XCD-aware
    const int RT = logical >> 2;                // 0..511 row tile
    const int j  = logical & 3;                 // 0..3 col group
    const int w = t >> 6, l = t & 63, g = l >> 4, l15 = l & 15;
    const int wr = w >> 2, wc = w & 3;

    int bn[4];
    bn[0] = (wc >> 1) * 64 + (wc & 1) * 32 + l15;
    bn[1] = bn[0] + 16;
    bn[2] = bn[0] + 128;
    bn[3] = bn[1] + 128;

    f32x4 acc[4][4];
    #pragma unroll
    for (int fc = 0; fc < 4; ++fc) {
        int colg = (fc < 2) ? (j * 128 + bn[fc]) : (512 + j * 128 + bn[fc] - 128);
        float bv = b2[colg];
        #pragma unroll
        for (int fr = 0; fr < 4; ++fr) acc[fr][fc] = (f32x4){bv, bv, bv, bv};
    }

    const char* hpb  = (const char*)hp;
    const char* w2sb = (const char*)W2S;
    const int lane16 = l * 16;

    #define STAGE(KT, B)                                                                     \
    {                                                                                        \
        size_t ga = ((size_t)(KT) * 65536 + (size_t)RT * 128) * 64 + w * 1024 + lane16;      \
        gload16(hpb + ga, (char*)&Ab[(B)][0] + w * 1024);                                    \
        size_t gb0 = ((size_t)(KT) * 1024 + j * 128) * 64 + w * 1024 + lane16;               \
        gload16(w2sb + gb0, (char*)&Bb[(B)][0] + w * 1024);                                  \
        size_t gb1 = ((size_t)(KT) * 1024 + 512 + j * 128) * 64 + w * 1024 + lane16;         \
        gload16(w2sb + gb1, (char*)&Bb[(B)][0] + 8192 + w * 1024);                           \
    }

    // prologue: tiles 0,1 in flight (6 loads)
    STAGE(0, 0);
    STAGE(1, 1);

    int cur = 0;
    for (int kt = 0; kt < 32; ++kt) {
        // wait for tile kt only: tile kt+1's 3 loads may stay in flight (never drain to 0)
        if (kt < 31) {
            asm volatile("s_waitcnt vmcnt(3)" ::: "memory");
        } else {
            asm volatile("s_waitcnt vmcnt(0)" ::: "memory");
        }
        __builtin_amdgcn_s_barrier();
        __builtin_amdgcn_sched_barrier(0);
        // stage kt+2 into the buffer freed at this barrier (readers of kt-1 all passed it)
        if (kt + 2 < 32) {
            int nb = cur + 2; if (nb >= 3) nb -= 3;
            STAGE(kt + 2, nb);
        }
        half8 aF[4], bF[4];
        const char* Abc = (const char*)&Ab[cur][0];
        const char* Bbc = (const char*)&Bb[cur][0];
        #pragma unroll
        for (int fr = 0; fr < 4; ++fr) {
            int r = wr * 64 + fr * 16 + l15;
            aF[fr] = *(const half8*)(Abc + r * 64 + ((g ^ ((r >> 1) & 3)) << 4));
        }
        #pragma unroll
        for (int fc = 0; fc < 4; ++fc) {
            int n = bn[fc];
            bF[fc] = *(const half8*)(Bbc + n * 64 + ((g ^ ((n >> 1) & 3)) << 4));
        }
        __builtin_amdgcn_s_setprio(1);
        #pragma unroll
        for (int fc = 0; fc < 4; ++fc)
            #pragma unroll
            for (int fr = 0; fr < 4; ++fr)
                acc[fr][fc] = __builtin_amdgcn_mfma_f32_16x16x32_f16(aF[fr], bF[fc], acc[fr][fc], 0, 0, 0);
        __builtin_amdgcn_s_setprio(0);
        cur = (cur == 2) ? 0 : cur + 1;
    }
    #undef STAGE

    // ---- epilogue: lp partials in-register (mu fc pairs var fc+2 in SAME lane) ----
    const int jj = j * 2 + (wc >> 1);
    float s[4][4];
    #pragma unroll
    for (int fr = 0; fr < 4; ++fr)
        #pragma unroll
        for (int rg = 0; rg < 4; ++rg) s[fr][rg] = 0.0f;

    #pragma unroll
    for (int fc = 0; fc < 2; ++fc) {
        int n = (wc & 1) * 32 + fc * 16 + l15;
        #pragma unroll
        for (int fr = 0; fr < 4; ++fr)
            #pragma unroll
            for (int rg = 0; rg < 4; ++rg) {
                int grow = RT * 128 + wr * 64 + fr * 16 + 4 * g + rg;
                int bp = (grow >> 3) + jj * 8192;
                float yv = y[(size_t)bp * 64 + n];
                float mu = acc[fr][fc][rg];
                float vr = acc[fr][fc + 2][rg];
                float vre = fmaxf(vr, LOG_1EM8);
                float iv = (vr >= LOG_1EM8) ? expf(-vr) : 1e8f;
                float d = yv - mu;
                s[fr][rg] += fmaf(d * d, iv, vre);
            }
    }
    #pragma unroll
    for (int fr = 0; fr < 4; ++fr)
        #pragma unroll
        for (int rg = 0; rg < 4; ++rg) {
            float v = s[fr][rg];
            v += __shfl_xor(v, 1); v += __shfl_xor(v, 2);
            v += __shfl_xor(v, 4); v += __shfl_xor(v, 8);
            s[fr][rg] = v;
        }
    if (l15 == 0) {
        #pragma unroll
        for (int fr = 0; fr < 4; ++fr)
            #pragma unroll
            for (int rg = 0; rg < 4; ++rg)
                lpp[wr * 64 + fr * 16 + 4 * g + rg][wc >> 1][wc & 1] = s[fr][rg];
    }
    __syncthreads();
    if (t < 256) {
        int row_l = t >> 1, m = t & 1;
        float lp = -0.5f * (lpp[row_l][m][0] + lpp[row_l][m][1]) - HALF_N_LOG2PI;
        int grow = RT * 128 + row_l;
        int bp = (grow >> 3) + (j * 2 + m) * 8192;
        lps[(size_t)bp * 8 + (grow & 7)] = lp;
    }
}

// ---------------- K3: pi network + log-softmax + logsumexp + block partial ----------------
__global__ __launch_bounds__(256)
void k3_pi(const float* __restrict__ x, const float* __restrict__ Wp1,
           const float* __restrict__ bp1, const float* __restrict__ Wp2,
           const float* __restrict__ bp2, const float* __restrict__ lps,
           float* __restrict__ partials)
{
    __shared__ float xsl[256][65];
    __shared__ float w1s[64][65];
    __shared__ float w2s[64][8];
    __shared__ float wsum[4];
    const int t = threadIdx.x;
    const int b0 = blockIdx.x * 256;

    {
        const float4* x4 = (const float4*)x;
        for (int i = 0; i < 16; ++i) {
            int idx = t + i * 256;
            int r = idx >> 4, c = idx & 15;
            float4 v = x4[(size_t)(b0 + r) * 16 + c];
            xsl[r][c*4+0] = v.x; xsl[r][c*4+1] = v.y;
            xsl[r][c*4+2] = v.z; xsl[r][c*4+3] = v.w;
        }
        for (int i = 0; i < 16; ++i) {
            int idx = t + i * 256;
            int r = idx >> 6, c = idx & 63;
            w1s[r][c] = Wp1[r * 64 + c];
        }
        ((float*)w2s)[t] = Wp2[t];
        ((float*)w2s)[t + 256] = Wp2[t + 256];
    }
    __syncthreads();

    float hid[64];
    #pragma unroll
    for (int c = 0; c < 64; ++c) hid[c] = bp1[c];
    for (int n = 0; n < 64; ++n) {
        float xv = xsl[t][n];
        #pragma unroll
        for (int c = 0; c < 64; ++c) hid[c] = fmaf(xv, w1s[n][c], hid[c]);
    }
    float lg[8];
    #pragma unroll
    for (int k = 0; k < 8; ++k) lg[k] = bp2[k];
    #pragma unroll
    for (int c = 0; c < 64; ++c) {
        float e = eluf(hid[c]);
        #pragma unroll
        for (int k = 0; k < 8; ++k) lg[k] = fmaf(e, w2s[c][k], lg[k]);
    }
    float4 lpa = *(const float4*)&lps[(size_t)(b0 + t) * 8];
    float4 lpb = *(const float4*)&lps[(size_t)(b0 + t) * 8 + 4];
    float lp[8] = {lpa.x, lpa.y, lpa.z, lpa.w, lpb.x, lpb.y, lpb.z, lpb.w};

    float m1 = lg[0];
    #pragma unroll
    for (int k = 1; k < 8; ++k) m1 = fmaxf(m1, lg[k]);
    float den = 0.0f;
    #pragma unroll
    for (int k = 0; k < 8; ++k) den += expf(lg[k] - m1);
    float lden = logf(den);

    float v0 = lg[0] - m1 - lden + lp[0];
    float m2 = v0;
    float vv[8]; vv[0] = v0;
    #pragma unroll
    for (int k = 1; k < 8; ++k) {
        vv[k] = lg[k] - m1 - lden + lp[k];
        m2 = fmaxf(m2, vv[k]);
    }
    float s2 = 0.0f;
    #pragma unroll
    for (int k = 0; k < 8; ++k) s2 += expf(vv[k] - m2);
    float loss = m2 + logf(s2);

    float ssum = loss;
    ssum += __shfl_xor(ssum, 1);  ssum += __shfl_xor(ssum, 2);
    ssum += __shfl_xor(ssum, 4);  ssum += __shfl_xor(ssum, 8);
    ssum += __shfl_xor(ssum, 16); ssum += __shfl_xor(ssum, 32);
    if ((t & 63) == 0) wsum[t >> 6] = ssum;
    __syncthreads();
    if (t == 0) partials[blockIdx.x] = wsum[0] + wsum[1] + wsum[2] + wsum[3];
}

// ---------------- K4: final reduce ----------------
__global__ void k4_reduce(const float* __restrict__ partials, float* __restrict__ out)
{
    __shared__ double red[256];
    int t = threadIdx.x;
    red[t] = (double)partials[t];
    __syncthreads();
    for (int s = 128; s > 0; s >>= 1) {
        if (t < s) red[t] += red[t + s];
        __syncthreads();
    }
    if (t == 0) out[0] = (float)(-red[0] / (double)B_TOT);
}

extern "C" void kernel_launch(void* const* d_in, const int* in_sizes, int n_in,
                              void* d_out, int out_size, void* d_ws, size_t ws_size,
                              hipStream_t stream)
{
    const float* x   = (const float*)d_in[0];
    const float* y   = (const float*)d_in[1];
    const float* W1  = (const float*)d_in[2];
    const float* b1  = (const float*)d_in[3];
    const float* W2  = (const float*)d_in[4];
    const float* b2  = (const float*)d_in[5];
    const float* Wp1 = (const float*)d_in[6];
    const float* bp1 = (const float*)d_in[7];
    const float* Wp2 = (const float*)d_in[8];
    const float* bp2 = (const float*)d_in[9];

    char* ws = (char*)d_ws;
    _Float16* W2S = (_Float16*)(ws + WS_W2S);
    _Float16* W1P = (_Float16*)(ws + WS_W1P);
    float* lps      = (float*)(ws + WS_LPS);
    float* partials = (float*)(ws + WS_PART);
    _Float16* hp    = (_Float16*)(ws + WS_HP);

    pack_w2s<<<dim3(16, 16), 256, 0, stream>>>(W2, W2S);
    pack_w1<<<dim3(1, 16), 256, 0, stream>>>(W1, W1P);
    k1_h<<<2048, 512, 0, stream>>>(x, W1P, b1, hp);
    k2_gemm2<<<2048, 512, 0, stream>>>(hp, W2S, b2, y, lps);
    k3_pi<<<256, 256, 0, stream>>>(x, Wp1, bp1, Wp2, bp2, lps, partials);
    k4_reduce<<<1, 256, 0, stream>>>(partials, (float*)d_out);
}

// Round 18
// 314.048 us; speedup vs baseline: 1.0702x; 1.0702x over previous
//
#include <hip/hip_runtime.h>
#include <math.h>

typedef __attribute__((ext_vector_type(8))) _Float16 half8;
typedef __attribute__((ext_vector_type(4))) _Float16 half4;
typedef __attribute__((ext_vector_type(4))) float f32x4;

#define B_TOT 65536
#define LOG2PI_F 1.8378770664093453f
#define HALF_N_LOG2PI (0.5f * 64.0f * LOG2PI_F)
#define LOG_1EM8 (-18.420680743952367f)

// ws layout (bytes)
#define WS_W2S  0                      // 2 MiB   fp16 packed+swizzled [32kt][1024n][32kk']
#define WS_W1P  (2u*1024*1024)         // 128 KiB fp16 packed [2kt][1024n][32kk] (plain)
#define WS_LPS  (4u*1024*1024)         // 2 MiB   float lps[65536][8]
#define WS_PART (6u*1024*1024)         // 1 KiB   float partials[256]

typedef __attribute__((address_space(3))) unsigned int lds_u32;
typedef const __attribute__((address_space(1))) unsigned int glb_u32;

__device__ __forceinline__ void gload16(const void* g, void* l) {
    __builtin_amdgcn_global_load_lds((glb_u32*)g, (lds_u32*)l, 16, 0, 0);
}

__device__ __forceinline__ float eluf(float v) {
    return v > 0.0f ? v : expm1f(v);
}

// ---------------- pack W1: fp32 [64][1024] -> fp16 [kt][n][32kk] plain ----------------
__global__ __launch_bounds__(256)
void pack_w1(const float* __restrict__ src, _Float16* __restrict__ dst)
{
    __shared__ float ts[64][65];
    const int t = threadIdx.x;
    const int n0 = blockIdx.y * 64;
    {
        int r = t >> 2, c4 = t & 3;
        for (int i = 0; i < 4; ++i) {
            int cc = i * 4 + c4;
            float4 v = *(const float4*)&src[(size_t)r * 1024 + n0 + cc * 4];
            ts[r][cc*4+0] = v.x; ts[r][cc*4+1] = v.y;
            ts[r][cc*4+2] = v.z; ts[r][cc*4+3] = v.w;
        }
    }
    __syncthreads();
    {
        int n = t >> 2;
        for (int i = 0; i < 4; ++i) {
            int k = (i * 4 + (t & 3)) * 4;      // 0..60
            half4 h;
            h.x = (_Float16)ts[k+0][n];
            h.y = (_Float16)ts[k+1][n];
            h.z = (_Float16)ts[k+2][n];
            h.w = (_Float16)ts[k+3][n];
            size_t off = (size_t)(k >> 5) * 32768 + (size_t)(n0 + n) * 32 + (k & 31);
            *(half4*)&dst[off] = h;
        }
    }
}

// ---------------- pack W2: fp32 [1024][1024] -> fp16 [kt][n][32] with k-group swizzle ----------------
// element (k, n) stored at [k>>5][n][ (slot<<3) | (k&7) ], slot = ((k>>3)&3) ^ ((n>>1)&3)
__global__ __launch_bounds__(256)
void pack_w2s(const float* __restrict__ src, _Float16* __restrict__ dst)
{
    __shared__ float ts[64][65];
    const int t = threadIdx.x;
    const int k0 = blockIdx.x * 64, n0 = blockIdx.y * 64;
    {
        int r = t >> 2, c4 = t & 3;
        for (int i = 0; i < 4; ++i) {
            int cc = i * 4 + c4;
            float4 v = *(const float4*)&src[(size_t)(k0 + r) * 1024 + n0 + cc * 4];
            ts[r][cc*4+0] = v.x; ts[r][cc*4+1] = v.y;
            ts[r][cc*4+2] = v.z; ts[r][cc*4+3] = v.w;
        }
    }
    __syncthreads();
    {
        int n = t >> 2;
        int ng = n0 + n;
        for (int i = 0; i < 4; ++i) {
            int kl = (i * 4 + (t & 3)) * 4;      // local k, 4-aligned
            int k = k0 + kl;
            half4 h;
            h.x = (_Float16)ts[kl+0][n];
            h.y = (_Float16)ts[kl+1][n];
            h.z = (_Float16)ts[kl+2][n];
            h.w = (_Float16)ts[kl+3][n];
            int kk = k & 31;
            int slot = ((kk >> 3) ^ ((ng >> 1) & 3));
            size_t off = (size_t)(k >> 5) * 32768 + (size_t)ng * 32 + (slot << 3) + (kk & 7);
            *(half4*)&dst[off] = h;
        }
    }
}

// ---------------- K2: fused GEMM1+GEMM2 + in-register lp epilogue ----------------
// Per block (RT, j): stage x_tile once; per kt compute next A-chunk in-block
// (swapped-operand GEMM1, round-16-verified layout math) into Ab[nxt] while
// GEMM2 consumes Ab[cur]/Bb[cur]. One barrier per iteration (round-16 skeleton).
__global__ __launch_bounds__(512)
void k2_fused(const float* __restrict__ x, const _Float16* __restrict__ W1P,
              const float* __restrict__ b1, const _Float16* __restrict__ W2S,
              const float* __restrict__ b2, const float* __restrict__ y,
              float* __restrict__ lps)
{
    __shared__ __align__(16) _Float16 xs[128 * 64];  // 16 KB  x_tile fp16 swizzled
    __shared__ __align__(16) _Float16 Ab[2][4096];   // 16 KB  [row' 128][32k] slot-swizzled
    __shared__ __align__(16) _Float16 Bb[2][8192];   // 32 KB  [n' 256][32k]
    __shared__ float lpp[128][2][2];                 // 2 KB

    const int t = threadIdx.x;
    const int bid = blockIdx.x;                 // 0..2047
    const int logical = (bid & 7) * 256 + (bid >> 3);   // XCD-aware
    const int RT = logical >> 2;                // 0..511 row tile
    const int j  = logical & 3;                 // 0..3 col group
    const int w = t >> 6, l = t & 63, g = l >> 4, l15 = l & 15;
    const int wr = w >> 2, wc = w & 3;

    int bn[4];
    bn[0] = (wc >> 1) * 64 + (wc & 1) * 32 + l15;
    bn[1] = bn[0] + 16;
    bn[2] = bn[0] + 128;
    bn[3] = bn[1] + 128;

    f32x4 acc[4][4];
    #pragma unroll
    for (int fc = 0; fc < 4; ++fc) {
        int colg = (fc < 2) ? (j * 128 + bn[fc]) : (512 + j * 128 + bn[fc] - 128);
        float bv = b2[colg];
        #pragma unroll
        for (int fr = 0; fr < 4; ++fr) acc[fr][fc] = (f32x4){bv, bv, bv, bv};
    }

    const char* w2sb = (const char*)W2S;
    const int lane16 = l * 16;

    #define STAGEB(KT, B)                                                                    \
    {                                                                                        \
        size_t gb0 = ((size_t)(KT) * 1024 + j * 128) * 64 + w * 1024 + lane16;               \
        gload16(w2sb + gb0, (char*)&Bb[(B)][0] + w * 1024);                                  \
        size_t gb1 = ((size_t)(KT) * 1024 + 512 + j * 128) * 64 + w * 1024 + lane16;         \
        gload16(w2sb + gb1, (char*)&Bb[(B)][0] + 8192 + w * 1024);                           \
    }

    // GEMM1 chunk for tile KT -> Ab[BUF]; wave w: rows (w&3)*32..+32, n-half (w>>2)
    #define COMPUTE_A(KT, BUF)                                                               \
    {                                                                                        \
        const int ktn = (KT) * 32 + (w >> 2) * 16;                                           \
        const int rowb = (w & 3) * 32;                                                       \
        f32x4 accA[2];                                                                       \
        float4 bv1 = *(const float4*)&b1[ktn + 4 * g];                                       \
        accA[0] = (f32x4){bv1.x, bv1.y, bv1.z, bv1.w};                                       \
        accA[1] = accA[0];                                                                   \
        _Pragma("unroll")                                                                    \
        for (int k0 = 0; k0 < 64; k0 += 32) {                                                \
            half8 aw = *(const half8*)&W1P[(size_t)(k0 >> 5) * 32768 + (size_t)(ktn + l15) * 32 + 8 * g]; \
            _Pragma("unroll")                                                                \
            for (int rf = 0; rf < 2; ++rf) {                                                 \
                int row = rowb + rf * 16 + l15;                                              \
                half8 bx = *(const half8*)&xs[row * 64 + ((k0 + 8 * g) ^ ((row & 7) << 3))]; \
                accA[rf] = __builtin_amdgcn_mfma_f32_16x16x32_f16(aw, bx, accA[rf], 0, 0, 0);\
            }                                                                                \
        }                                                                                    \
        const int kkhi = (w >> 2) * 2 + (g >> 1);                                            \
        const int kklo = 4 * (g & 1);                                                        \
        _Pragma("unroll")                                                                    \
        for (int rf = 0; rf < 2; ++rf) {                                                     \
            int row = rowb + rf * 16 + l15;                                                  \
            int slot = kkhi ^ ((row >> 1) & 3);                                              \
            half4 h4;                                                                        \
            h4.x = (_Float16)eluf(accA[rf][0]);                                              \
            h4.y = (_Float16)eluf(accA[rf][1]);                                              \
            h4.z = (_Float16)eluf(accA[rf][2]);                                              \
            h4.w = (_Float16)eluf(accA[rf][3]);                                              \
            *(half4*)&Ab[(BUF)][row * 32 + slot * 8 + kklo] = h4;                            \
        }                                                                                    \
    }

    // ---------- prologue: stage x_tile (fp16, swizzled) ----------
    {
        const float4* x4 = (const float4*)x;
        int r = t >> 2, c4 = t & 3;
        #pragma unroll
        for (int i = 0; i < 4; ++i) {
            int c = c4 * 4 + i;
            float4 v = x4[(size_t)(RT * 128 + r) * 16 + c];
            float vv[4] = {v.x, v.y, v.z, v.w};
            #pragma unroll
            for (int u = 0; u < 4; ++u) {
                int col = c * 4 + u;
                xs[r * 64 + (col ^ ((r & 7) << 3))] = (_Float16)vv[u];
            }
        }
    }
    __syncthreads();
    COMPUTE_A(0, 0);
    STAGEB(0, 0);
    __syncthreads();

    for (int kt = 0; kt < 32; ++kt) {
        const int cur = kt & 1, nxt = cur ^ 1;
        if (kt < 31) STAGEB(kt + 1, nxt);
        half8 aF[4], bF[4];
        const char* Abc = (const char*)&Ab[cur][0];
        const char* Bbc = (const char*)&Bb[cur][0];
        #pragma unroll
        for (int fr = 0; fr < 4; ++fr) {
            int r = wr * 64 + fr * 16 + l15;
            aF[fr] = *(const half8*)(Abc + r * 64 + ((g ^ ((r >> 1) & 3)) << 4));
        }
        #pragma unroll
        for (int fc = 0; fc < 4; ++fc) {
            int n = bn[fc];
            bF[fc] = *(const half8*)(Bbc + n * 64 + ((g ^ ((n >> 1) & 3)) << 4));
        }
        #pragma unroll
        for (int fc = 0; fc < 4; ++fc)
            #pragma unroll
            for (int fr = 0; fr < 4; ++fr)
                acc[fr][fc] = __builtin_amdgcn_mfma_f32_16x16x32_f16(aF[fr], bF[fc], acc[fr][fc], 0, 0, 0);
        if (kt < 31) COMPUTE_A(kt + 1, nxt);
        __syncthreads();
    }
    #undef STAGEB
    #undef COMPUTE_A

    // ---- epilogue: lp partials in-register (mu fc pairs var fc+2 in SAME lane) ----
    const int jj = j * 2 + (wc >> 1);
    float s[4][4];
    #pragma unroll
    for (int fr = 0; fr < 4; ++fr)
        #pragma unroll
        for (int rg = 0; rg < 4; ++rg) s[fr][rg] = 0.0f;

    #pragma unroll
    for (int fc = 0; fc < 2; ++fc) {
        int n = (wc & 1) * 32 + fc * 16 + l15;
        #pragma unroll
        for (int fr = 0; fr < 4; ++fr)
            #pragma unroll
            for (int rg = 0; rg < 4; ++rg) {
                int grow = RT * 128 + wr * 64 + fr * 16 + 4 * g + rg;
                int bp = (grow >> 3) + jj * 8192;
                float yv = y[(size_t)bp * 64 + n];
                float mu = acc[fr][fc][rg];
                float vr = acc[fr][fc + 2][rg];
                float vre = fmaxf(vr, LOG_1EM8);
                float iv = (vr >= LOG_1EM8) ? expf(-vr) : 1e8f;
                float d = yv - mu;
                s[fr][rg] += fmaf(d * d, iv, vre);
            }
    }
    #pragma unroll
    for (int fr = 0; fr < 4; ++fr)
        #pragma unroll
        for (int rg = 0; rg < 4; ++rg) {
            float v = s[fr][rg];
            v += __shfl_xor(v, 1); v += __shfl_xor(v, 2);
            v += __shfl_xor(v, 4); v += __shfl_xor(v, 8);
            s[fr][rg] = v;
        }
    if (l15 == 0) {
        #pragma unroll
        for (int fr = 0; fr < 4; ++fr)
            #pragma unroll
            for (int rg = 0; rg < 4; ++rg)
                lpp[wr * 64 + fr * 16 + 4 * g + rg][wc >> 1][wc & 1] = s[fr][rg];
    }
    __syncthreads();
    if (t < 256) {
        int row_l = t >> 1, m = t & 1;
        float lp = -0.5f * (lpp[row_l][m][0] + lpp[row_l][m][1]) - HALF_N_LOG2PI;
        int grow = RT * 128 + row_l;
        int bp = (grow >> 3) + (j * 2 + m) * 8192;
        lps[(size_t)bp * 8 + (grow & 7)] = lp;
    }
}

// ---------------- K3: pi network + log-softmax + logsumexp + block partial ----------------
__global__ __launch_bounds__(256)
void k3_pi(const float* __restrict__ x, const float* __restrict__ Wp1,
           const float* __restrict__ bp1, const float* __restrict__ Wp2,
           const float* __restrict__ bp2, const float* __restrict__ lps,
           float* __restrict__ partials)
{
    __shared__ float xsl[256][65];
    __shared__ float w1s[64][65];
    __shared__ float w2s[64][8];
    __shared__ float wsum[4];
    const int t = threadIdx.x;
    const int b0 = blockIdx.x * 256;

    {
        const float4* x4 = (const float4*)x;
        for (int i = 0; i < 16; ++i) {
            int idx = t + i * 256;
            int r = idx >> 4, c = idx & 15;
            float4 v = x4[(size_t)(b0 + r) * 16 + c];
            xsl[r][c*4+0] = v.x; xsl[r][c*4+1] = v.y;
            xsl[r][c*4+2] = v.z; xsl[r][c*4+3] = v.w;
        }
        for (int i = 0; i < 16; ++i) {
            int idx = t + i * 256;
            int r = idx >> 6, c = idx & 63;
            w1s[r][c] = Wp1[r * 64 + c];
        }
        ((float*)w2s)[t] = Wp2[t];
        ((float*)w2s)[t + 256] = Wp2[t + 256];
    }
    __syncthreads();

    float hid[64];
    #pragma unroll
    for (int c = 0; c < 64; ++c) hid[c] = bp1[c];
    for (int n = 0; n < 64; ++n) {
        float xv = xsl[t][n];
        #pragma unroll
        for (int c = 0; c < 64; ++c) hid[c] = fmaf(xv, w1s[n][c], hid[c]);
    }
    float lg[8];
    #pragma unroll
    for (int k = 0; k < 8; ++k) lg[k] = bp2[k];
    #pragma unroll
    for (int c = 0; c < 64; ++c) {
        float e = eluf(hid[c]);
        #pragma unroll
        for (int k = 0; k < 8; ++k) lg[k] = fmaf(e, w2s[c][k], lg[k]);
    }
    float4 lpa = *(const float4*)&lps[(size_t)(b0 + t) * 8];
    float4 lpb = *(const float4*)&lps[(size_t)(b0 + t) * 8 + 4];
    float lp[8] = {lpa.x, lpa.y, lpa.z, lpa.w, lpb.x, lpb.y, lpb.z, lpb.w};

    float m1 = lg[0];
    #pragma unroll
    for (int k = 1; k < 8; ++k) m1 = fmaxf(m1, lg[k]);
    float den = 0.0f;
    #pragma unroll
    for (int k = 0; k < 8; ++k) den += expf(lg[k] - m1);
    float lden = logf(den);

    float v0 = lg[0] - m1 - lden + lp[0];
    float m2 = v0;
    float vv[8]; vv[0] = v0;
    #pragma unroll
    for (int k = 1; k < 8; ++k) {
        vv[k] = lg[k] - m1 - lden + lp[k];
        m2 = fmaxf(m2, vv[k]);
    }
    float s2 = 0.0f;
    #pragma unroll
    for (int k = 0; k < 8; ++k) s2 += expf(vv[k] - m2);
    float loss = m2 + logf(s2);

    float ssum = loss;
    ssum += __shfl_xor(ssum, 1);  ssum += __shfl_xor(ssum, 2);
    ssum += __shfl_xor(ssum, 4);  ssum += __shfl_xor(ssum, 8);
    ssum += __shfl_xor(ssum, 16); ssum += __shfl_xor(ssum, 32);
    if ((t & 63) == 0) wsum[t >> 6] = ssum;
    __syncthreads();
    if (t == 0) partials[blockIdx.x] = wsum[0] + wsum[1] + wsum[2] + wsum[3];
}

// ---------------- K4: final reduce ----------------
__global__ void k4_reduce(const float* __restrict__ partials, float* __restrict__ out)
{
    __shared__ double red[256];
    int t = threadIdx.x;
    red[t] = (double)partials[t];
    __syncthreads();
    for (int s = 128; s > 0; s >>= 1) {
        if (t < s) red[t] += red[t + s];
        __syncthreads();
    }
    if (t == 0) out[0] = (float)(-red[0] / (double)B_TOT);
}

extern "C" void kernel_launch(void* const* d_in, const int* in_sizes, int n_in,
                              void* d_out, int out_size, void* d_ws, size_t ws_size,
                              hipStream_t stream)
{
    const float* x   = (const float*)d_in[0];
    const float* y   = (const float*)d_in[1];
    const float* W1  = (const float*)d_in[2];
    const float* b1  = (const float*)d_in[3];
    const float* W2  = (const float*)d_in[4];
    const float* b2  = (const float*)d_in[5];
    const float* Wp1 = (const float*)d_in[6];
    const float* bp1 = (const float*)d_in[7];
    const float* Wp2 = (const float*)d_in[8];
    const float* bp2 = (const float*)d_in[9];

    char* ws = (char*)d_ws;
    _Float16* W2S = (_Float16*)(ws + WS_W2S);
    _Float16* W1P = (_Float16*)(ws + WS_W1P);
    float* lps      = (float*)(ws + WS_LPS);
    float* partials = (float*)(ws + WS_PART);

    pack_w2s<<<dim3(16, 16), 256, 0, stream>>>(W2, W2S);
    pack_w1<<<dim3(1, 16), 256, 0, stream>>>(W1, W1P);
    k2_fused<<<2048, 512, 0, stream>>>(x, W1P, b1, W2S, b2, y, lps);
    k3_pi<<<256, 256, 0, stream>>>(x, Wp1, bp1, Wp2, bp2, lps, partials);
    k4_reduce<<<1, 256, 0, stream>>>(partials, (float*)d_out);
}

// Round 19
// 246.752 us; speedup vs baseline: 1.3620x; 1.2727x over previous
//
#include <hip/hip_runtime.h>
#include <math.h>

typedef __attribute__((ext_vector_type(8))) _Float16 half8;
typedef __attribute__((ext_vector_type(4))) _Float16 half4;
typedef __attribute__((ext_vector_type(4))) float f32x4;

#define B_TOT 65536
#define LOG2PI_F 1.8378770664093453f
#define HALF_N_LOG2PI (0.5f * 64.0f * LOG2PI_F)
#define LOG_1EM8 (-18.420680743952367f)

// ws layout (bytes)
#define WS_W2S  0                      // 2 MiB   fp16 packed+swizzled [32kt][1024n][32kk']
#define WS_W1P  (2u*1024*1024)         // 128 KiB fp16 packed [2kt][1024n][32kk] (plain)
#define WS_LPS  (4u*1024*1024)         // 2 MiB   float lps[65536][8]
#define WS_PART (6u*1024*1024)         // 1 KiB   float partials[256]

typedef __attribute__((address_space(3))) unsigned int lds_u32;
typedef const __attribute__((address_space(1))) unsigned int glb_u32;

__device__ __forceinline__ void gload16(const void* g, void* l) {
    __builtin_amdgcn_global_load_lds((glb_u32*)g, (lds_u32*)l, 16, 0, 0);
}

// fast ELU: native v_exp_f32 (~4 ops) instead of expm1f's ~22-op polynomial.
// |error| vs expm1f ~1e-8 abs — 3 orders below the fp16 storage rounding.
__device__ __forceinline__ float eluf(float v) {
    return v > 0.0f ? v : __expf(v) - 1.0f;
}

// ---------------- pack W1: fp32 [64][1024] -> fp16 [kt][n][32kk] plain ----------------
__global__ __launch_bounds__(256)
void pack_w1(const float* __restrict__ src, _Float16* __restrict__ dst)
{
    __shared__ float ts[64][65];
    const int t = threadIdx.x;
    const int n0 = blockIdx.y * 64;
    {
        int r = t >> 2, c4 = t & 3;
        for (int i = 0; i < 4; ++i) {
            int cc = i * 4 + c4;
            float4 v = *(const float4*)&src[(size_t)r * 1024 + n0 + cc * 4];
            ts[r][cc*4+0] = v.x; ts[r][cc*4+1] = v.y;
            ts[r][cc*4+2] = v.z; ts[r][cc*4+3] = v.w;
        }
    }
    __syncthreads();
    {
        int n = t >> 2;
        for (int i = 0; i < 4; ++i) {
            int k = (i * 4 + (t & 3)) * 4;      // 0..60
            half4 h;
            h.x = (_Float16)ts[k+0][n];
            h.y = (_Float16)ts[k+1][n];
            h.z = (_Float16)ts[k+2][n];
            h.w = (_Float16)ts[k+3][n];
            size_t off = (size_t)(k >> 5) * 32768 + (size_t)(n0 + n) * 32 + (k & 31);
            *(half4*)&dst[off] = h;
        }
    }
}

// ---------------- pack W2: fp32 [1024][1024] -> fp16 [kt][n][32] with k-group swizzle ----------------
// element (k, n) stored at [k>>5][n][ (slot<<3) | (k&7) ], slot = ((k>>3)&3) ^ ((n>>1)&3)
__global__ __launch_bounds__(256)
void pack_w2s(const float* __restrict__ src, _Float16* __restrict__ dst)
{
    __shared__ float ts[64][65];
    const int t = threadIdx.x;
    const int k0 = blockIdx.x * 64, n0 = blockIdx.y * 64;
    {
        int r = t >> 2, c4 = t & 3;
        for (int i = 0; i < 4; ++i) {
            int cc = i * 4 + c4;
            float4 v = *(const float4*)&src[(size_t)(k0 + r) * 1024 + n0 + cc * 4];
            ts[r][cc*4+0] = v.x; ts[r][cc*4+1] = v.y;
            ts[r][cc*4+2] = v.z; ts[r][cc*4+3] = v.w;
        }
    }
    __syncthreads();
    {
        int n = t >> 2;
        int ng = n0 + n;
        for (int i = 0; i < 4; ++i) {
            int kl = (i * 4 + (t & 3)) * 4;      // local k, 4-aligned
            int k = k0 + kl;
            half4 h;
            h.x = (_Float16)ts[kl+0][n];
            h.y = (_Float16)ts[kl+1][n];
            h.z = (_Float16)ts[kl+2][n];
            h.w = (_Float16)ts[kl+3][n];
            int kk = k & 31;
            int slot = ((kk >> 3) ^ ((ng >> 1) & 3));
            size_t off = (size_t)(k >> 5) * 32768 + (size_t)ng * 32 + (slot << 3) + (kk & 7);
            *(half4*)&dst[off] = h;
        }
    }
}

// ---------------- K2: fused GEMM1+GEMM2 + in-register lp epilogue ----------------
// Per block (RT, j): stage x_tile once; per kt compute next A-chunk in-block
// (swapped-operand GEMM1) into Ab[nxt] while GEMM2 consumes Ab[cur]/Bb[cur].
// One barrier per iteration. Round-18 structure; ONLY delta = fast ELU.
__global__ __launch_bounds__(512)
void k2_fused(const float* __restrict__ x, const _Float16* __restrict__ W1P,
              const float* __restrict__ b1, const _Float16* __restrict__ W2S,
              const float* __restrict__ b2, const float* __restrict__ y,
              float* __restrict__ lps)
{
    __shared__ __align__(16) _Float16 xs[128 * 64];  // 16 KB  x_tile fp16 swizzled
    __shared__ __align__(16) _Float16 Ab[2][4096];   // 16 KB  [row' 128][32k] slot-swizzled
    __shared__ __align__(16) _Float16 Bb[2][8192];   // 32 KB  [n' 256][32k]
    __shared__ float lpp[128][2][2];                 // 2 KB

    const int t = threadIdx.x;
    const int bid = blockIdx.x;                 // 0..2047
    const int logical = (bid & 7) * 256 + (bid >> 3);   // XCD-aware
    const int RT = logical >> 2;                // 0..511 row tile
    const int j  = logical & 3;                 // 0..3 col group
    const int w = t >> 6, l = t & 63, g = l >> 4, l15 = l & 15;
    const int wr = w >> 2, wc = w & 3;

    int bn[4];
    bn[0] = (wc >> 1) * 64 + (wc & 1) * 32 + l15;
    bn[1] = bn[0] + 16;
    bn[2] = bn[0] + 128;
    bn[3] = bn[1] + 128;

    f32x4 acc[4][4];
    #pragma unroll
    for (int fc = 0; fc < 4; ++fc) {
        int colg = (fc < 2) ? (j * 128 + bn[fc]) : (512 + j * 128 + bn[fc] - 128);
        float bv = b2[colg];
        #pragma unroll
        for (int fr = 0; fr < 4; ++fr) acc[fr][fc] = (f32x4){bv, bv, bv, bv};
    }

    const char* w2sb = (const char*)W2S;
    const int lane16 = l * 16;

    #define STAGEB(KT, B)                                                                    \
    {                                                                                        \
        size_t gb0 = ((size_t)(KT) * 1024 + j * 128) * 64 + w * 1024 + lane16;               \
        gload16(w2sb + gb0, (char*)&Bb[(B)][0] + w * 1024);                                  \
        size_t gb1 = ((size_t)(KT) * 1024 + 512 + j * 128) * 64 + w * 1024 + lane16;         \
        gload16(w2sb + gb1, (char*)&Bb[(B)][0] + 8192 + w * 1024);                           \
    }

    // GEMM1 chunk for tile KT -> Ab[BUF]; wave w: rows (w&3)*32..+32, n-half (w>>2)
    #define COMPUTE_A(KT, BUF)                                                               \
    {                                                                                        \
        const int ktn = (KT) * 32 + (w >> 2) * 16;                                           \
        const int rowb = (w & 3) * 32;                                                       \
        f32x4 accA[2];                                                                       \
        float4 bv1 = *(const float4*)&b1[ktn + 4 * g];                                       \
        accA[0] = (f32x4){bv1.x, bv1.y, bv1.z, bv1.w};                                       \
        accA[1] = accA[0];                                                                   \
        _Pragma("unroll")                                                                    \
        for (int k0 = 0; k0 < 64; k0 += 32) {                                                \
            half8 aw = *(const half8*)&W1P[(size_t)(k0 >> 5) * 32768 + (size_t)(ktn + l15) * 32 + 8 * g]; \
            _Pragma("unroll")                                                                \
            for (int rf = 0; rf < 2; ++rf) {                                                 \
                int row = rowb + rf * 16 + l15;                                              \
                half8 bx = *(const half8*)&xs[row * 64 + ((k0 + 8 * g) ^ ((row & 7) << 3))]; \
                accA[rf] = __builtin_amdgcn_mfma_f32_16x16x32_f16(aw, bx, accA[rf], 0, 0, 0);\
            }                                                                                \
        }                                                                                    \
        const int kkhi = (w >> 2) * 2 + (g >> 1);                                            \
        const int kklo = 4 * (g & 1);                                                        \
        _Pragma("unroll")                                                                    \
        for (int rf = 0; rf < 2; ++rf) {                                                     \
            int row = rowb + rf * 16 + l15;                                                  \
            int slot = kkhi ^ ((row >> 1) & 3);                                              \
            half4 h4;                                                                        \
            h4.x = (_Float16)eluf(accA[rf][0]);                                              \
            h4.y = (_Float16)eluf(accA[rf][1]);                                              \
            h4.z = (_Float16)eluf(accA[rf][2]);                                              \
            h4.w = (_Float16)eluf(accA[rf][3]);                                              \
            *(half4*)&Ab[(BUF)][row * 32 + slot * 8 + kklo] = h4;                            \
        }                                                                                    \
    }

    // ---------- prologue: stage x_tile (fp16, swizzled) ----------
    {
        const float4* x4 = (const float4*)x;
        int r = t >> 2, c4 = t & 3;
        #pragma unroll
        for (int i = 0; i < 4; ++i) {
            int c = c4 * 4 + i;
            float4 v = x4[(size_t)(RT * 128 + r) * 16 + c];
            float vv[4] = {v.x, v.y, v.z, v.w};
            #pragma unroll
            for (int u = 0; u < 4; ++u) {
                int col = c * 4 + u;
                xs[r * 64 + (col ^ ((r & 7) << 3))] = (_Float16)vv[u];
            }
        }
    }
    __syncthreads();
    COMPUTE_A(0, 0);
    STAGEB(0, 0);
    __syncthreads();

    for (int kt = 0; kt < 32; ++kt) {
        const int cur = kt & 1, nxt = cur ^ 1;
        if (kt < 31) STAGEB(kt + 1, nxt);
        half8 aF[4], bF[4];
        const char* Abc = (const char*)&Ab[cur][0];
        const char* Bbc = (const char*)&Bb[cur][0];
        #pragma unroll
        for (int fr = 0; fr < 4; ++fr) {
            int r = wr * 64 + fr * 16 + l15;
            aF[fr] = *(const half8*)(Abc + r * 64 + ((g ^ ((r >> 1) & 3)) << 4));
        }
        #pragma unroll
        for (int fc = 0; fc < 4; ++fc) {
            int n = bn[fc];
            bF[fc] = *(const half8*)(Bbc + n * 64 + ((g ^ ((n >> 1) & 3)) << 4));
        }
        #pragma unroll
        for (int fc = 0; fc < 4; ++fc)
            #pragma unroll
            for (int fr = 0; fr < 4; ++fr)
                acc[fr][fc] = __builtin_amdgcn_mfma_f32_16x16x32_f16(aF[fr], bF[fc], acc[fr][fc], 0, 0, 0);
        if (kt < 31) COMPUTE_A(kt + 1, nxt);
        __syncthreads();
    }
    #undef STAGEB
    #undef COMPUTE_A

    // ---- epilogue: lp partials in-register (mu fc pairs var fc+2 in SAME lane) ----
    const int jj = j * 2 + (wc >> 1);
    float s[4][4];
    #pragma unroll
    for (int fr = 0; fr < 4; ++fr)
        #pragma unroll
        for (int rg = 0; rg < 4; ++rg) s[fr][rg] = 0.0f;

    #pragma unroll
    for (int fc = 0; fc < 2; ++fc) {
        int n = (wc & 1) * 32 + fc * 16 + l15;
        #pragma unroll
        for (int fr = 0; fr < 4; ++fr)
            #pragma unroll
            for (int rg = 0; rg < 4; ++rg) {
                int grow = RT * 128 + wr * 64 + fr * 16 + 4 * g + rg;
                int bp = (grow >> 3) + jj * 8192;
                float yv = y[(size_t)bp * 64 + n];
                float mu = acc[fr][fc][rg];
                float vr = acc[fr][fc + 2][rg];
                float vre = fmaxf(vr, LOG_1EM8);
                float iv = (vr >= LOG_1EM8) ? expf(-vr) : 1e8f;
                float d = yv - mu;
                s[fr][rg] += fmaf(d * d, iv, vre);
            }
    }
    #pragma unroll
    for (int fr = 0; fr < 4; ++fr)
        #pragma unroll
        for (int rg = 0; rg < 4; ++rg) {
            float v = s[fr][rg];
            v += __shfl_xor(v, 1); v += __shfl_xor(v, 2);
            v += __shfl_xor(v, 4); v += __shfl_xor(v, 8);
            s[fr][rg] = v;
        }
    if (l15 == 0) {
        #pragma unroll
        for (int fr = 0; fr < 4; ++fr)
            #pragma unroll
            for (int rg = 0; rg < 4; ++rg)
                lpp[wr * 64 + fr * 16 + 4 * g + rg][wc >> 1][wc & 1] = s[fr][rg];
    }
    __syncthreads();
    if (t < 256) {
        int row_l = t >> 1, m = t & 1;
        float lp = -0.5f * (lpp[row_l][m][0] + lpp[row_l][m][1]) - HALF_N_LOG2PI;
        int grow = RT * 128 + row_l;
        int bp = (grow >> 3) + (j * 2 + m) * 8192;
        lps[(size_t)bp * 8 + (grow & 7)] = lp;
    }
}

// ---------------- K3: pi network + log-softmax + logsumexp + block partial ----------------
__global__ __launch_bounds__(256)
void k3_pi(const float* __restrict__ x, const float* __restrict__ Wp1,
           const float* __restrict__ bp1, const float* __restrict__ Wp2,
           const float* __restrict__ bp2, const float* __restrict__ lps,
           float* __restrict__ partials)
{
    __shared__ float xsl[256][65];
    __shared__ float w1s[64][65];
    __shared__ float w2s[64][8];
    __shared__ float wsum[4];
    const int t = threadIdx.x;
    const int b0 = blockIdx.x * 256;

    {
        const float4* x4 = (const float4*)x;
        for (int i = 0; i < 16; ++i) {
            int idx = t + i * 256;
            int r = idx >> 4, c = idx & 15;
            float4 v = x4[(size_t)(b0 + r) * 16 + c];
            xsl[r][c*4+0] = v.x; xsl[r][c*4+1] = v.y;
            xsl[r][c*4+2] = v.z; xsl[r][c*4+3] = v.w;
        }
        for (int i = 0; i < 16; ++i) {
            int idx = t + i * 256;
            int r = idx >> 6, c = idx & 63;
            w1s[r][c] = Wp1[r * 64 + c];
        }
        ((float*)w2s)[t] = Wp2[t];
        ((float*)w2s)[t + 256] = Wp2[t + 256];
    }
    __syncthreads();

    float hid[64];
    #pragma unroll
    for (int c = 0; c < 64; ++c) hid[c] = bp1[c];
    for (int n = 0; n < 64; ++n) {
        float xv = xsl[t][n];
        #pragma unroll
        for (int c = 0; c < 64; ++c) hid[c] = fmaf(xv, w1s[n][c], hid[c]);
    }
    float lg[8];
    #pragma unroll
    for (int k = 0; k < 8; ++k) lg[k] = bp2[k];
    #pragma unroll
    for (int c = 0; c < 64; ++c) {
        float e = eluf(hid[c]);
        #pragma unroll
        for (int k = 0; k < 8; ++k) lg[k] = fmaf(e, w2s[c][k], lg[k]);
    }
    float4 lpa = *(const float4*)&lps[(size_t)(b0 + t) * 8];
    float4 lpb = *(const float4*)&lps[(size_t)(b0 + t) * 8 + 4];
    float lp[8] = {lpa.x, lpa.y, lpa.z, lpa.w, lpb.x, lpb.y, lpb.z, lpb.w};

    float m1 = lg[0];
    #pragma unroll
    for (int k = 1; k < 8; ++k) m1 = fmaxf(m1, lg[k]);
    float den = 0.0f;
    #pragma unroll
    for (int k = 0; k < 8; ++k) den += expf(lg[k] - m1);
    float lden = logf(den);

    float v0 = lg[0] - m1 - lden + lp[0];
    float m2 = v0;
    float vv[8]; vv[0] = v0;
    #pragma unroll
    for (int k = 1; k < 8; ++k) {
        vv[k] = lg[k] - m1 - lden + lp[k];
        m2 = fmaxf(m2, vv[k]);
    }
    float s2 = 0.0f;
    #pragma unroll
    for (int k = 0; k < 8; ++k) s2 += expf(vv[k] - m2);
    float loss = m2 + logf(s2);

    float ssum = loss;
    ssum += __shfl_xor(ssum, 1);  ssum += __shfl_xor(ssum, 2);
    ssum += __shfl_xor(ssum, 4);  ssum += __shfl_xor(ssum, 8);
    ssum += __shfl_xor(ssum, 16); ssum += __shfl_xor(ssum, 32);
    if ((t & 63) == 0) wsum[t >> 6] = ssum;
    __syncthreads();
    if (t == 0) partials[blockIdx.x] = wsum[0] + wsum[1] + wsum[2] + wsum[3];
}

// ---------------- K4: final reduce ----------------
__global__ void k4_reduce(const float* __restrict__ partials, float* __restrict__ out)
{
    __shared__ double red[256];
    int t = threadIdx.x;
    red[t] = (double)partials[t];
    __syncthreads();
    for (int s = 128; s > 0; s >>= 1) {
        if (t < s) red[t] += red[t + s];
        __syncthreads();
    }
    if (t == 0) out[0] = (float)(-red[0] / (double)B_TOT);
}

extern "C" void kernel_launch(void* const* d_in, const int* in_sizes, int n_in,
                              void* d_out, int out_size, void* d_ws, size_t ws_size,
                              hipStream_t stream)
{
    const float* x   = (const float*)d_in[0];
    const float* y   = (const float*)d_in[1];
    const float* W1  = (const float*)d_in[2];
    const float* b1  = (const float*)d_in[3];
    const float* W2  = (const float*)d_in[4];
    const float* b2  = (const float*)d_in[5];
    const float* Wp1 = (const float*)d_in[6];
    const float* bp1 = (const float*)d_in[7];
    const float* Wp2 = (const float*)d_in[8];
    const float* bp2 = (const float*)d_in[9];

    char* ws = (char*)d_ws;
    _Float16* W2S = (_Float16*)(ws + WS_W2S);
    _Float16* W1P = (_Float16*)(ws + WS_W1P);
    float* lps      = (float*)(ws + WS_LPS);
    float* partials = (float*)(ws + WS_PART);

    pack_w2s<<<dim3(16, 16), 256, 0, stream>>>(W2, W2S);
    pack_w1<<<dim3(1, 16), 256, 0, stream>>>(W1, W1P);
    k2_fused<<<2048, 512, 0, stream>>>(x, W1P, b1, W2S, b2, y, lps);
    k3_pi<<<256, 256, 0, stream>>>(x, Wp1, bp1, Wp2, bp2, lps, partials);
    k4_reduce<<<1, 256, 0, stream>>>(partials, (float*)d_out);
}

// Round 20
// 224.743 us; speedup vs baseline: 1.4954x; 1.0979x over previous
//
#include <hip/hip_runtime.h>
#include <math.h>

typedef __attribute__((ext_vector_type(8))) _Float16 half8;
typedef __attribute__((ext_vector_type(4))) _Float16 half4;
typedef __attribute__((ext_vector_type(4))) float f32x4;

#define B_TOT 65536
#define LOG2PI_F 1.8378770664093453f
#define HALF_N_LOG2PI (0.5f * 64.0f * LOG2PI_F)
#define LOG_1EM8 (-18.420680743952367f)

// ws layout (bytes)
#define WS_W2S  0                      // 2 MiB   fp16 packed+swizzled [32kt][1024n][32kk']
#define WS_W1P  (2u*1024*1024)         // 128 KiB fp16 packed [2kt][1024n][32kk] (plain)
#define WS_LPS  (4u*1024*1024)         // 2 MiB   float lps[65536][8]
#define WS_PART (6u*1024*1024)         // 1 KiB   float partials[256]
#define WS_HP   (8u*1024*1024)         // 128 MiB fp16 h packed [32kt][65536row][32kk']

typedef __attribute__((address_space(3))) unsigned int lds_u32;
typedef const __attribute__((address_space(1))) unsigned int glb_u32;

__device__ __forceinline__ void gload16(const void* g, void* l) {
    __builtin_amdgcn_global_load_lds((glb_u32*)g, (lds_u32*)l, 16, 0, 0);
}

// fast ELU: native v_exp_f32 path (~4 ops) instead of expm1f's ~22-op polynomial.
__device__ __forceinline__ float eluf(float v) {
    return v > 0.0f ? v : __expf(v) - 1.0f;
}

// ---------------- pack W1: fp32 [64][1024] -> fp16 [kt][n][32kk] plain ----------------
__global__ __launch_bounds__(256)
void pack_w1(const float* __restrict__ src, _Float16* __restrict__ dst)
{
    __shared__ float ts[64][65];
    const int t = threadIdx.x;
    const int n0 = blockIdx.y * 64;
    {
        int r = t >> 2, c4 = t & 3;
        for (int i = 0; i < 4; ++i) {
            int cc = i * 4 + c4;
            float4 v = *(const float4*)&src[(size_t)r * 1024 + n0 + cc * 4];
            ts[r][cc*4+0] = v.x; ts[r][cc*4+1] = v.y;
            ts[r][cc*4+2] = v.z; ts[r][cc*4+3] = v.w;
        }
    }
    __syncthreads();
    {
        int n = t >> 2;
        for (int i = 0; i < 4; ++i) {
            int k = (i * 4 + (t & 3)) * 4;      // 0..60
            half4 h;
            h.x = (_Float16)ts[k+0][n];
            h.y = (_Float16)ts[k+1][n];
            h.z = (_Float16)ts[k+2][n];
            h.w = (_Float16)ts[k+3][n];
            size_t off = (size_t)(k >> 5) * 32768 + (size_t)(n0 + n) * 32 + (k & 31);
            *(half4*)&dst[off] = h;
        }
    }
}

// ---------------- pack W2: fp32 [1024][1024] -> fp16 [kt][n][32] with k-group swizzle ----------------
// element (k, n) stored at [k>>5][n][ (slot<<3) | (k&7) ], slot = ((k>>3)&3) ^ ((n>>1)&3)
__global__ __launch_bounds__(256)
void pack_w2s(const float* __restrict__ src, _Float16* __restrict__ dst)
{
    __shared__ float ts[64][65];
    const int t = threadIdx.x;
    const int k0 = blockIdx.x * 64, n0 = blockIdx.y * 64;
    {
        int r = t >> 2, c4 = t & 3;
        for (int i = 0; i < 4; ++i) {
            int cc = i * 4 + c4;
            float4 v = *(const float4*)&src[(size_t)(k0 + r) * 1024 + n0 + cc * 4];
            ts[r][cc*4+0] = v.x; ts[r][cc*4+1] = v.y;
            ts[r][cc*4+2] = v.z; ts[r][cc*4+3] = v.w;
        }
    }
    __syncthreads();
    {
        int n = t >> 2;
        int ng = n0 + n;
        for (int i = 0; i < 4; ++i) {
            int kl = (i * 4 + (t & 3)) * 4;      // local k, 4-aligned
            int k = k0 + kl;
            half4 h;
            h.x = (_Float16)ts[kl+0][n];
            h.y = (_Float16)ts[kl+1][n];
            h.z = (_Float16)ts[kl+2][n];
            h.w = (_Float16)ts[kl+3][n];
            int kk = k & 31;
            int slot = ((kk >> 3) ^ ((ng >> 1) & 3));
            size_t off = (size_t)(k >> 5) * 32768 + (size_t)ng * 32 + (slot << 3) + (kk & 7);
            *(half4*)&dst[off] = h;
        }
    }
}

// ---------------- K1: h = elu(x @ W1 + b1) -> hp, swapped-operand MFMA + LDS-staged coalesced store ----
// Swapped mfma(A=W1frag, B=xfrag): lane's 4 rg values = 4 consecutive k (round-16-verified).
// Epilogue: half4 ds_writes into a 64KB stage in hp's exact chunk layout, then half8
// fully-coalesced global stores (1KB/wave-instr) — fixes round-16's 25%-efficiency scatter.
__global__ __launch_bounds__(512)
void k1_h(const float* __restrict__ x, const _Float16* __restrict__ W1P,
          const float* __restrict__ b1, _Float16* __restrict__ hp)
{
    __shared__ __align__(16) _Float16 xs[32 * 64];    // 4 KB
    __shared__ __align__(16) _Float16 stage[32768];   // 64 KB: [kt 32][row 32][32kk']
    const int t = threadIdx.x, q = blockIdx.x;
    const int w = t >> 6, l = t & 63, g = l >> 4, l15 = l & 15;

    {
        const float4* x4 = (const float4*)x;
        int r = t >> 4, c = t & 15;
        float4 v = x4[(size_t)(q * 32 + r) * 16 + c];
        float vv[4] = {v.x, v.y, v.z, v.w};
        #pragma unroll
        for (int i = 0; i < 4; ++i) {
            int col = c * 4 + i;
            xs[r * 64 + (col ^ ((r & 7) << 3))] = (_Float16)vv[i];
        }
    }
    __syncthreads();

    // wave w owns n in [w*128, w*128+128): 8 n-frags; 2 row-frags (32 rows)
    f32x4 acc[8][2];
    const float4* b1_4 = (const float4*)b1;
    #pragma unroll
    for (int nf = 0; nf < 8; ++nf) {
        float4 bv = b1_4[(w * 128 + nf * 16 + 4 * g) >> 2];   // bias by n (varies with rg)
        acc[nf][0] = (f32x4){bv.x, bv.y, bv.z, bv.w};
        acc[nf][1] = acc[nf][0];
    }
    #pragma unroll
    for (int k0 = 0; k0 < 64; k0 += 32) {
        half8 bx[2];
        #pragma unroll
        for (int rf = 0; rf < 2; ++rf) {
            int row = rf * 16 + l15;
            bx[rf] = *(const half8*)&xs[row * 64 + ((k0 + 8 * g) ^ ((row & 7) << 3))];
        }
        #pragma unroll
        for (int nf = 0; nf < 8; ++nf) {
            size_t off = (size_t)(k0 >> 5) * 32768 + (size_t)(w * 128 + nf * 16 + l15) * 32 + 8 * g;
            half8 aw = *(const half8*)&W1P[off];
            #pragma unroll
            for (int rf = 0; rf < 2; ++rf)
                acc[nf][rf] = __builtin_amdgcn_mfma_f32_16x16x32_f16(aw, bx[rf], acc[nf][rf], 0, 0, 0);
        }
    }
    // epilogue: ELU -> half4 ds_writes into stage (hp chunk layout; (grow>>1)&3 == (row>>1)&3)
    #pragma unroll
    for (int nf = 0; nf < 8; ++nf) {
        int kt = w * 4 + (nf >> 1);
        int kkhi = (nf & 1) * 2 + (g >> 1);   // kk>>3
        int kklo = 4 * (g & 1);               // kk&7 base (rg adds 0..3)
        #pragma unroll
        for (int rf = 0; rf < 2; ++rf) {
            int row = rf * 16 + l15;
            int slot = kkhi ^ ((row >> 1) & 3);
            half4 h4;
            h4.x = (_Float16)eluf(acc[nf][rf][0]);
            h4.y = (_Float16)eluf(acc[nf][rf][1]);
            h4.z = (_Float16)eluf(acc[nf][rf][2]);
            h4.w = (_Float16)eluf(acc[nf][rf][3]);
            *(half4*)&stage[kt * 1024 + row * 32 + slot * 8 + kklo] = h4;
        }
    }
    __syncthreads();
    // coalesced copy: consecutive threads write consecutive 16B; per kt one 2KB run in hp
    #pragma unroll
    for (int i = 0; i < 8; ++i) {
        int f8 = (i * 512 + t) * 8;     // half index into stage
        int kt = f8 >> 10;
        int rem = f8 & 1023;
        *(half8*)&hp[(size_t)kt * 2097152 + (size_t)q * 1024 + rem] = *(const half8*)&stage[f8];
    }
}

// ---------------- K2: fhatx = h @ W2 + b2 (round-16 structure) + in-register lp epilogue ----------------
__global__ __launch_bounds__(512)
void k2_gemm2(const _Float16* __restrict__ hp, const _Float16* __restrict__ W2S,
              const float* __restrict__ b2, const float* __restrict__ y,
              float* __restrict__ lps)
{
    __shared__ __align__(16) _Float16 Ab[2][4096];   // 2 x 8 KB  [row' 128][32k]
    __shared__ __align__(16) _Float16 Bb[2][8192];   // 2 x 16 KB [n' 256][32k]
    __shared__ float lpp[128][2][2];                 // 2 KB

    const int t = threadIdx.x;
    const int bid = blockIdx.x;                 // 0..2047
    const int logical = (bid & 7) * 256 + (bid >> 3);   // XCD-aware
    const int RT = logical >> 2;                // 0..511 row tile
    const int j  = logical & 3;                 // 0..3 col group
    const int w = t >> 6, l = t & 63, g = l >> 4, l15 = l & 15;
    const int wr = w >> 2, wc = w & 3;

    int bn[4];
    bn[0] = (wc >> 1) * 64 + (wc & 1) * 32 + l15;
    bn[1] = bn[0] + 16;
    bn[2] = bn[0] + 128;
    bn[3] = bn[1] + 128;

    f32x4 acc[4][4];
    #pragma unroll
    for (int fc = 0; fc < 4; ++fc) {
        int colg = (fc < 2) ? (j * 128 + bn[fc]) : (512 + j * 128 + bn[fc] - 128);
        float bv = b2[colg];
        #pragma unroll
        for (int fr = 0; fr < 4; ++fr) acc[fr][fc] = (f32x4){bv, bv, bv, bv};
    }

    const char* hpb  = (const char*)hp;
    const char* w2sb = (const char*)W2S;
    const int lane16 = l * 16;

    {
        size_t ga = ((size_t)0 * 65536 + (size_t)RT * 128) * 64 + w * 1024 + lane16;
        gload16(hpb + ga, (char*)&Ab[0][0] + w * 1024);
        size_t gb0 = ((size_t)0 * 1024 + j * 128) * 64 + w * 1024 + lane16;
        gload16(w2sb + gb0, (char*)&Bb[0][0] + w * 1024);
        size_t gb1 = ((size_t)0 * 1024 + 512 + j * 128) * 64 + w * 1024 + lane16;
        gload16(w2sb + gb1, (char*)&Bb[0][0] + 8192 + w * 1024);
    }
    __syncthreads();

    for (int kt = 0; kt < 32; ++kt) {
        int cur = kt & 1;
        if (kt < 31) {
            int nx = cur ^ 1;
            size_t ga = ((size_t)(kt + 1) * 65536 + (size_t)RT * 128) * 64 + w * 1024 + lane16;
            gload16(hpb + ga, (char*)&Ab[nx][0] + w * 1024);
            size_t gb0 = ((size_t)(kt + 1) * 1024 + j * 128) * 64 + w * 1024 + lane16;
            gload16(w2sb + gb0, (char*)&Bb[nx][0] + w * 1024);
            size_t gb1 = ((size_t)(kt + 1) * 1024 + 512 + j * 128) * 64 + w * 1024 + lane16;
            gload16(w2sb + gb1, (char*)&Bb[nx][0] + 8192 + w * 1024);
        }
        half8 aF[4], bF[4];
        #pragma unroll
        for (int fr = 0; fr < 4; ++fr) {
            int r = wr * 64 + fr * 16 + l15;
            aF[fr] = *(const half8*)((const char*)&Ab[cur][0] + r * 64 + ((g ^ ((r >> 1) & 3)) << 4));
        }
        #pragma unroll
        for (int fc = 0; fc < 4; ++fc) {
            int n = bn[fc];
            bF[fc] = *(const half8*)((const char*)&Bb[cur][0] + n * 64 + ((g ^ ((n >> 1) & 3)) << 4));
        }
        #pragma unroll
        for (int fc = 0; fc < 4; ++fc)
            #pragma unroll
            for (int fr = 0; fr < 4; ++fr)
                acc[fr][fc] = __builtin_amdgcn_mfma_f32_16x16x32_f16(aF[fr], bF[fc], acc[fr][fc], 0, 0, 0);
        __syncthreads();
    }

    // ---- epilogue: lp partials in-register (mu fc pairs var fc+2 in SAME lane) ----
    const int jj = j * 2 + (wc >> 1);
    float s[4][4];
    #pragma unroll
    for (int fr = 0; fr < 4; ++fr)
        #pragma unroll
        for (int rg = 0; rg < 4; ++rg) s[fr][rg] = 0.0f;

    #pragma unroll
    for (int fc = 0; fc < 2; ++fc) {
        int n = (wc & 1) * 32 + fc * 16 + l15;
        #pragma unroll
        for (int fr = 0; fr < 4; ++fr)
            #pragma unroll
            for (int rg = 0; rg < 4; ++rg) {
                int grow = RT * 128 + wr * 64 + fr * 16 + 4 * g + rg;
                int bp = (grow >> 3) + jj * 8192;
                float yv = y[(size_t)bp * 64 + n];
                float mu = acc[fr][fc][rg];
                float vr = acc[fr][fc + 2][rg];
                float vre = fmaxf(vr, LOG_1EM8);
                float iv = (vr >= LOG_1EM8) ? expf(-vr) : 1e8f;
                float d = yv - mu;
                s[fr][rg] += fmaf(d * d, iv, vre);
            }
    }
    #pragma unroll
    for (int fr = 0; fr < 4; ++fr)
        #pragma unroll
        for (int rg = 0; rg < 4; ++rg) {
            float v = s[fr][rg];
            v += __shfl_xor(v, 1); v += __shfl_xor(v, 2);
            v += __shfl_xor(v, 4); v += __shfl_xor(v, 8);
            s[fr][rg] = v;
        }
    if (l15 == 0) {
        #pragma unroll
        for (int fr = 0; fr < 4; ++fr)
            #pragma unroll
            for (int rg = 0; rg < 4; ++rg)
                lpp[wr * 64 + fr * 16 + 4 * g + rg][wc >> 1][wc & 1] = s[fr][rg];
    }
    __syncthreads();
    if (t < 256) {
        int row_l = t >> 1, m = t & 1;
        float lp = -0.5f * (lpp[row_l][m][0] + lpp[row_l][m][1]) - HALF_N_LOG2PI;
        int grow = RT * 128 + row_l;
        int bp = (grow >> 3) + (j * 2 + m) * 8192;
        lps[(size_t)bp * 8 + (grow & 7)] = lp;
    }
}

// ---------------- K3: pi network + log-softmax + logsumexp + block partial ----------------
__global__ __launch_bounds__(256)
void k3_pi(const float* __restrict__ x, const float* __restrict__ Wp1,
           const float* __restrict__ bp1, const float* __restrict__ Wp2,
           const float* __restrict__ bp2, const float* __restrict__ lps,
           float* __restrict__ partials)
{
    __shared__ float xsl[256][65];
    __shared__ float w1s[64][65];
    __shared__ float w2s[64][8];
    __shared__ float wsum[4];
    const int t = threadIdx.x;
    const int b0 = blockIdx.x * 256;

    {
        const float4* x4 = (const float4*)x;
        for (int i = 0; i < 16; ++i) {
            int idx = t + i * 256;
            int r = idx >> 4, c = idx & 15;
            float4 v = x4[(size_t)(b0 + r) * 16 + c];
            xsl[r][c*4+0] = v.x; xsl[r][c*4+1] = v.y;
            xsl[r][c*4+2] = v.z; xsl[r][c*4+3] = v.w;
        }
        for (int i = 0; i < 16; ++i) {
            int idx = t + i * 256;
            int r = idx >> 6, c = idx & 63;
            w1s[r][c] = Wp1[r * 64 + c];
        }
        ((float*)w2s)[t] = Wp2[t];
        ((float*)w2s)[t + 256] = Wp2[t + 256];
    }
    __syncthreads();

    float hid[64];
    #pragma unroll
    for (int c = 0; c < 64; ++c) hid[c] = bp1[c];
    for (int n = 0; n < 64; ++n) {
        float xv = xsl[t][n];
        #pragma unroll
        for (int c = 0; c < 64; ++c) hid[c] = fmaf(xv, w1s[n][c], hid[c]);
    }
    float lg[8];
    #pragma unroll
    for (int k = 0; k < 8; ++k) lg[k] = bp2[k];
    #pragma unroll
    for (int c = 0; c < 64; ++c) {
        float e = eluf(hid[c]);
        #pragma unroll
        for (int k = 0; k < 8; ++k) lg[k] = fmaf(e, w2s[c][k], lg[k]);
    }
    float4 lpa = *(const float4*)&lps[(size_t)(b0 + t) * 8];
    float4 lpb = *(const float4*)&lps[(size_t)(b0 + t) * 8 + 4];
    float lp[8] = {lpa.x, lpa.y, lpa.z, lpa.w, lpb.x, lpb.y, lpb.z, lpb.w};

    float m1 = lg[0];
    #pragma unroll
    for (int k = 1; k < 8; ++k) m1 = fmaxf(m1, lg[k]);
    float den = 0.0f;
    #pragma unroll
    for (int k = 0; k < 8; ++k) den += expf(lg[k] - m1);
    float lden = logf(den);

    float v0 = lg[0] - m1 - lden + lp[0];
    float m2 = v0;
    float vv[8]; vv[0] = v0;
    #pragma unroll
    for (int k = 1; k < 8; ++k) {
        vv[k] = lg[k] - m1 - lden + lp[k];
        m2 = fmaxf(m2, vv[k]);
    }
    float s2 = 0.0f;
    #pragma unroll
    for (int k = 0; k < 8; ++k) s2 += expf(vv[k] - m2);
    float loss = m2 + logf(s2);

    float ssum = loss;
    ssum += __shfl_xor(ssum, 1);  ssum += __shfl_xor(ssum, 2);
    ssum += __shfl_xor(ssum, 4);  ssum += __shfl_xor(ssum, 8);
    ssum += __shfl_xor(ssum, 16); ssum += __shfl_xor(ssum, 32);
    if ((t & 63) == 0) wsum[t >> 6] = ssum;
    __syncthreads();
    if (t == 0) partials[blockIdx.x] = wsum[0] + wsum[1] + wsum[2] + wsum[3];
}

// ---------------- K4: final reduce ----------------
__global__ void k4_reduce(const float* __restrict__ partials, float* __restrict__ out)
{
    __shared__ double red[256];
    int t = threadIdx.x;
    red[t] = (double)partials[t];
    __syncthreads();
    for (int s = 128; s > 0; s >>= 1) {
        if (t < s) red[t] += red[t + s];
        __syncthreads();
    }
    if (t == 0) out[0] = (float)(-red[0] / (double)B_TOT);
}

extern "C" void kernel_launch(void* const* d_in, const int* in_sizes, int n_in,
                              void* d_out, int out_size, void* d_ws, size_t ws_size,
                              hipStream_t stream)
{
    const float* x   = (const float*)d_in[0];
    const float* y   = (const float*)d_in[1];
    const float* W1  = (const float*)d_in[2];
    const float* b1  = (const float*)d_in[3];
    const float* W2  = (const float*)d_in[4];
    const float* b2  = (const float*)d_in[5];
    const float* Wp1 = (const float*)d_in[6];
    const float* bp1 = (const float*)d_in[7];
    const float* Wp2 = (const float*)d_in[8];
    const float* bp2 = (const float*)d_in[9];

    char* ws = (char*)d_ws;
    _Float16* W2S = (_Float16*)(ws + WS_W2S);
    _Float16* W1P = (_Float16*)(ws + WS_W1P);
    float* lps      = (float*)(ws + WS_LPS);
    float* partials = (float*)(ws + WS_PART);
    _Float16* hp    = (_Float16*)(ws + WS_HP);

    pack_w2s<<<dim3(16, 16), 256, 0, stream>>>(W2, W2S);
    pack_w1<<<dim3(1, 16), 256, 0, stream>>>(W1, W1P);
    k1_h<<<2048, 512, 0, stream>>>(x, W1P, b1, hp);
    k2_gemm2<<<2048, 512, 0, stream>>>(hp, W2S, b2, y, lps);
    k3_pi<<<256, 256, 0, stream>>>(x, Wp1, bp1, Wp2, bp2, lps, partials);
    k4_reduce<<<1, 256, 0, stream>>>(partials, (float*)d_out);
}